// Round 3
// baseline (553.799 us; speedup 1.0000x reference)
//
#include <hip/hip_runtime.h>
#include <hip/hip_bf16.h>

typedef unsigned short u16;
typedef __attribute__((ext_vector_type(8))) short short8;
typedef __attribute__((ext_vector_type(4))) short short4_t;
typedef __attribute__((ext_vector_type(4))) float floatx4;

#define MFMA16(A, B, C) __builtin_amdgcn_mfma_f32_16x16x32_bf16((A), (B), (C), 0, 0, 0)

// ws layout (u16 element offsets)
#define OF_SPEC  64                       // canonical bf16 spec [204800]
#define OF_SMALL (OF_SPEC + 204800)       // W1(0) b1(256) fq(512) fk(768) fv(1024)
#define OF_PART  (OF_SMALL + 1536)        // 8x256 f32 partials for fused bp (4096 u16)
#define OF_FW    (OF_PART + 4096)         // fused weights frag-major: Wq' Wk' Wv' (3x65536) + Wp'(524288)

static __device__ __forceinline__ float bf2f(u16 u) {
  union { unsigned int i; float f; } z; z.i = ((unsigned int)u) << 16; return z.f;
}
static __device__ __forceinline__ u16 f2bf(float f) {
  union { float f; unsigned int i; } z; z.f = f;
  unsigned int x = z.i + 0x7fffu + ((z.i >> 16) & 1u);  // RNE
  return (u16)(x >> 16);
}
static __device__ __forceinline__ unsigned pkbf(float lo, float hi) {
  __hip_bfloat162 h = __float22bfloat162_rn(make_float2(lo, hi));  // RNE pair cvt
  unsigned r; __builtin_memcpy(&r, &h, 4); return r;
}
static __device__ __forceinline__ void ld8f(const u16* p, float* o) {
  union { short8 v; u16 u[8]; } t;
  t.v = *(const short8*)p;
#pragma unroll
  for (int j = 0; j < 8; ++j) o[j] = bf2f(t.u[j]);
}

// bf16 (0) vs f32 (1) input detection on first 256 u16 of spec; per-wave ballot.
static __device__ __forceinline__ int detect_flag(const u16* __restrict__ sp) {
  const int lane = threadIdx.x & 63;
  int bad = 0;
#pragma unroll
  for (int j = 0; j < 4; ++j) {
    u16 v = sp[lane * 4 + j];
    int e = (v >> 7) & 0xFF;
    bad += (e >= 137);
  }
  return (__popcll(__ballot(bad > 0)) >= 4) ? 1 : 0;
}

#define CV(src, idx) (flag ? f2bf(((const float*)(src))[idx]) : ((const u16*)(src))[idx])

// One launch, flag hoisted out of all hot loops:
//   blocks 0..99   : canonicalize spec (8 elems/thread, vectorized)
//   block  100     : canonicalize W1, b1
//   blocks 101..276: 11 fold GEMMs of 256x256x256 (16 sub-blocks of 64x64 each)
//       g=0..2:  Wg' = W2 @ {Wq,Wk,Wv}
//       g=3..10: Wp'_p = Wo @ Wp[p*256:...]
//       written bf16 fragment-major: dst[(k>>3)*2048 + n*8 + (k&7)]
//   blocks 277..287: fused bias vectors fq/fk/fv + 8 f32 partials for fb
__global__ void prep_kernel(
    const void* spec, const void* W1, const void* b1, const void* W2, const void* b2,
    const void* Wq, const void* bq, const void* Wk, const void* bk, const void* Wv,
    const void* bv_, const void* Wo, const void* bo, const void* Wp, const void* bp,
    u16* __restrict__ ws) {
  const int flag = detect_flag((const u16*)spec);
  const int b = blockIdx.x, tid = threadIdx.x;
  if (b < 100) {
    const int i = (b * 256 + tid) * 8;
    union { short8 s8; u16 u[8]; } t;
    if (flag) {
      const float* s = (const float*)spec + i;
      floatx4 v0 = *(const floatx4*)s, v1 = *(const floatx4*)(s + 4);
#pragma unroll
      for (int j = 0; j < 4; ++j) { t.u[j] = f2bf(v0[j]); t.u[4 + j] = f2bf(v1[j]); }
    } else {
      t.s8 = *((const short8*)spec + (b * 256 + tid));
    }
    *(short8*)(ws + OF_SPEC + i) = t.s8;
    return;
  }
  if (b == 100) {
    ws[OF_SMALL + tid] = CV(W1, tid);
    ws[OF_SMALL + 256 + tid] = CV(b1, tid);
    return;
  }
  const int f = b - 101;
  if (f >= 176) {
    const int t = f - 176, n = tid;
    if (t < 3) {
      const void* SB = (t == 0) ? Wq : (t == 1) ? Wk : Wv;
      const void* bs = (t == 0) ? bq : (t == 1) ? bk : bv_;
      float acc;
      if (flag) {
        acc = ((const float*)bs)[n];
        const float* Bf = (const float*)SB; const float* b2f = (const float*)b2;
        for (int k = 0; k < 256; ++k) acc = fmaf(b2f[k], Bf[k * 256 + n], acc);
      } else {
        acc = bf2f(((const u16*)bs)[n]);
        const u16* Bh = (const u16*)SB; const u16* b2h = (const u16*)b2;
        for (int k = 0; k < 256; ++k) acc = fmaf(bf2f(b2h[k]), bf2f(Bh[k * 256 + n]), acc);
      }
      ws[OF_SMALL + 512 + t * 256 + n] = f2bf(acc);
    } else {
      const int p = t - 3;
      float acc = 0.f;
      if (flag) {
        const float* Wf = (const float*)Wp; const float* bf = (const float*)bo;
        for (int m = 0; m < 256; ++m) acc = fmaf(bf[m], Wf[(p * 256 + m) * 256 + n], acc);
      } else {
        const u16* Wh = (const u16*)Wp; const u16* bh = (const u16*)bo;
        for (int m = 0; m < 256; ++m)
          acc = fmaf(bf2f(bh[m]), bf2f(Wh[(p * 256 + m) * 256 + n]), acc);
      }
      ((float*)(ws + OF_PART))[p * 256 + n] = acc;
    }
    return;
  }
  // fold GEMMs
  const int g = f >> 4, sub = f & 15;
  const int r0 = (sub >> 2) * 64, c0 = (sub & 3) * 64;
  const void* SA = (g < 3) ? W2 : Wo;
  const void* SB = (g == 0) ? Wq : (g == 1) ? Wk : (g == 2) ? Wv : Wp;
  const int brow0 = (g < 3) ? 0 : (g - 3) * 256;
  const int w = tid >> 6, lane = tid & 63, l15 = lane & 15, quad = lane >> 4;
  const int arow = r0 + w * 16 + l15;
  floatx4 acc[4];
#pragma unroll
  for (int ni = 0; ni < 4; ++ni) acc[ni] = (floatx4){0.f, 0.f, 0.f, 0.f};
  if (flag) {
    const float* A = (const float*)SA; const float* B = (const float*)SB;
    for (int kc = 0; kc < 8; ++kc) {
      const int k0 = kc * 32 + quad * 8;
      floatx4 a0 = *(const floatx4*)(A + arow * 256 + k0);
      floatx4 a1 = *(const floatx4*)(A + arow * 256 + k0 + 4);
      union { short8 s8; u16 u[8]; } av;
#pragma unroll
      for (int j = 0; j < 4; ++j) { av.u[j] = f2bf(a0[j]); av.u[4 + j] = f2bf(a1[j]); }
#pragma unroll
      for (int ni = 0; ni < 4; ++ni) {
        const int colx = c0 + ni * 16 + l15;
        union { short8 s8; u16 u[8]; } bu;
#pragma unroll
        for (int j = 0; j < 8; ++j) bu.u[j] = f2bf(B[(brow0 + k0 + j) * 256 + colx]);
        acc[ni] = MFMA16(av.s8, bu.s8, acc[ni]);
      }
    }
  } else {
    const u16* A = (const u16*)SA; const u16* B = (const u16*)SB;
    for (int kc = 0; kc < 8; ++kc) {
      const int k0 = kc * 32 + quad * 8;
      short8 av = *(const short8*)(A + arow * 256 + k0);
#pragma unroll
      for (int ni = 0; ni < 4; ++ni) {
        const int colx = c0 + ni * 16 + l15;
        union { short8 s8; u16 u[8]; } bu;
#pragma unroll
        for (int j = 0; j < 8; ++j) bu.u[j] = B[(brow0 + k0 + j) * 256 + colx];
        acc[ni] = MFMA16(av, bu.s8, acc[ni]);
      }
    }
  }
  u16* dst = ws + OF_FW + ((g < 3) ? g * 65536 : 3 * 65536);
#pragma unroll
  for (int ni = 0; ni < 4; ++ni) {
    const int n = c0 + ni * 16 + l15;
#pragma unroll
    for (int r = 0; r < 4; ++r) {
      const int k = brow0 + r0 + w * 16 + quad * 4 + r;
      dst[(k >> 3) * 2048 + n * 8 + (k & 7)] = f2bf(acc[ni][r]);
    }
  }
}

// One block = 64 tokens = 8 windows, fully fused. No a-tile in LDS: MFMA
// A-fragments of a = relu(s*W1+b1) are recomputed in-register per chunk.
// Patch projection runs incrementally per chunk from an 8 KB o-slice buffer.
// LDS = 32 KB -> 4 blocks/CU (VGPR-capped via launch_bounds).
__global__ __launch_bounds__(256, 4) void fused_kernel(
    const u16* __restrict__ spec_raw,
    const u16* __restrict__ csp, const u16* __restrict__ csm,
    const u16* __restrict__ sWq, const u16* __restrict__ sWk,
    const u16* __restrict__ sWv, const u16* __restrict__ sWp,
    const void* __restrict__ bp, const float* __restrict__ part,
    void* __restrict__ out)
{
  __shared__ u16 lds[16384];          // 32768 B
  u16* qb  = lds;                     // 64 x 64, XOR-swizzled cols (+ wave-local P scratch)
  u16* kb  = lds + 4096;
  u16* vbT = lds + 8192;              // transposed V, swizzled tok-blocks
  u16* oS  = lds + 12288;             // per-chunk o-slice [64 k8-blocks][8 win][8 elems]

  const u16* cW1 = csm;
  const u16* cb1 = csm + 256;
  const u16* cfq = csm + 512;
  const u16* cfk = csm + 768;
  const u16* cfv = csm + 1024;

  const int flag = detect_flag(spec_raw);
  const int tid = threadIdx.x;
  const int wave = tid >> 6, lane = tid & 63;
  const int l15 = lane & 15, quad = lane >> 4;
  const int tile0 = blockIdx.x * 64;
  const floatx4 zero4 = (floatx4){0.f, 0.f, 0.f, 0.f};

  float sv[4];
#pragma unroll
  for (int mi = 0; mi < 4; ++mi) sv[mi] = bf2f(csp[tile0 + mi * 16 + l15]);

  floatx4 pacc[4];
#pragma unroll
  for (int ni = 0; ni < 4; ++ni) pacc[ni] = zero4;

  // q,k,v GEMMs for chunk c; A-fragments recomputed in-register.
  auto qkv_gemm = [&](int c) {
    const int col = c * 64 + wave * 16 + l15;
    floatx4 facc[3][4];
#pragma unroll
    for (int x = 0; x < 3; ++x)
#pragma unroll
      for (int mi = 0; mi < 4; ++mi) facc[x][mi] = zero4;
    for (int kc = 0; kc < 8; ++kc) {
      const int k0 = (kc * 4 + quad) * 8;
      float w1f[8], b1f[8];
      ld8f(cW1 + k0, w1f);
      ld8f(cb1 + k0, b1f);
      const int wo = (k0 * 32 + col) * 8;
      short8 bq8 = *(const short8*)(sWq + wo);
      short8 bk8 = *(const short8*)(sWk + wo);
      short8 bv8 = *(const short8*)(sWv + wo);
#pragma unroll
      for (int mi = 0; mi < 4; ++mi) {
        union { short8 s8; unsigned u[4]; } av;
#pragma unroll
        for (int j = 0; j < 4; ++j) {
          float x0 = fmaxf(fmaf(sv[mi], w1f[2 * j],     b1f[2 * j]),     0.f);
          float x1 = fmaxf(fmaf(sv[mi], w1f[2 * j + 1], b1f[2 * j + 1]), 0.f);
          av.u[j] = pkbf(x0, x1);
        }
        facc[0][mi] = MFMA16(av.s8, bq8, facc[0][mi]);
        facc[1][mi] = MFMA16(av.s8, bk8, facc[1][mi]);
        facc[2][mi] = MFMA16(av.s8, bv8, facc[2][mi]);
      }
    }
    const int lc = wave * 16 + l15;
    const float bqv = bf2f(cfq[col]), bkv = bf2f(cfk[col]), bvv = bf2f(cfv[col]);
#pragma unroll
    for (int mi = 0; mi < 4; ++mi) {
#pragma unroll
      for (int r = 0; r < 4; ++r) {
        const int tr = mi * 16 + quad * 4 + r;
        const int rr = tr * 64 + ((((lc >> 3) ^ (tr & 7)) << 3) | (lc & 7));
        qb[rr] = f2bf(facc[0][mi][r] + bqv);
        kb[rr] = f2bf(facc[1][mi][r] + bkv);
      }
      union { short4_t s4; u16 u[4]; } tv;
#pragma unroll
      for (int r = 0; r < 4; ++r) tv.u[r] = f2bf(facc[2][mi][r] + bvv);
      *(short4_t*)(vbT + lc * 64 + (((mi * 2 + (quad >> 1)) ^ (lc & 7)) << 3) +
                   (quad & 1) * 4) = tv.s4;
    }
  };

  // MFMA attention: wave w owns windows {2w,2w+1}, both heads of chunk c.
  // Writes o-slice straight into oS (patch-frag-major for this chunk).
  auto attention = [&](int c) {
    (void)c;
    const int w2 = wave * 2;
    const int rq = (wave * 16 + l15) * 64;
    u16* pscr = qb + wave * 1024;     // aliases this wave's own Q rows (reads done first)
    const int validk = ((l15 >> 3) == (quad >> 1));

    floatx4 sc2[2];
#pragma unroll
    for (int hl = 0; hl < 2; ++hl) {
      const int c8s = (((hl * 4 + quad) ^ (l15 & 7)) << 3);
      short8 qf = *(const short8*)(qb + rq + c8s);
      short8 kf = *(const short8*)(kb + rq + c8s);
      sc2[hl] = MFMA16(qf, kf, zero4);
    }
    u16 pb[2][4];
#pragma unroll
    for (int hl = 0; hl < 2; ++hl) {
#pragma unroll
      for (int r = 0; r < 4; ++r) {
        float s = sc2[hl][r] * 0.17677669529663687f;   // 1/sqrt(32)
        float mx = fmaxf(s, __shfl_xor(s, 1));
        mx = fmaxf(mx, __shfl_xor(mx, 2));
        mx = fmaxf(mx, __shfl_xor(mx, 4));
        float p = __expf(s - mx);
        float sum = p + __shfl_xor(p, 1);
        sum += __shfl_xor(sum, 2);
        sum += __shfl_xor(sum, 4);
        pb[hl][r] = f2bf(validk ? p / sum : 0.f);
      }
    }
#pragma unroll
    for (int hl = 0; hl < 2; ++hl)
#pragma unroll
      for (int r = 0; r < 4; ++r)
        pscr[hl * 256 + (quad * 4 + r) * 16 + l15] = pb[hl][r];

    const int obase = (2 * wave + (quad >> 1)) * 8 + (l15 & 7);
    const int pb4 = (quad & 1) * 4;
#pragma unroll
    for (int hl = 0; hl < 2; ++hl) {
#pragma unroll
      for (int dh = 0; dh < 2; ++dh) {
        const int vcol = hl * 32 + dh * 16 + l15;
        short8 pa = (short8){0, 0, 0, 0, 0, 0, 0, 0};
        short8 vf = (short8){0, 0, 0, 0, 0, 0, 0, 0};
        if (quad < 2) {
          pa = *(const short8*)(pscr + hl * 256 + l15 * 16 + quad * 8);
          vf = *(const short8*)(vbT + vcol * 64 + (((w2 + quad) ^ (vcol & 7)) << 3));
        }
        floatx4 o = MFMA16(pa, vf, zero4);
        const int e = hl * 4 + dh * 2 + (l15 >> 3);
#pragma unroll
        for (int r = 0; r < 4; ++r)
          oS[((pb4 + r) * 8 + e) * 64 + obase] = f2bf(o[r]);
      }
    }
  };

  // Partial patch projection: this chunk's 16 K-blocks of [8 x 2048] @ Wp'.
  // A-frag lanes 8..15 broadcast rows 0..7 (outputs discarded).
  auto patch_partial = [&](int c) {
    const int w8 = (l15 & 7) * 8;
#pragma unroll
    for (int kcl = 0; kcl < 16; ++kcl) {
      const int p = kcl >> 1, h = kcl & 1;
      short8 afr = *(const short8*)(oS + (p * 8 + h * 4 + quad) * 64 + w8);
      const int kg = p * 8 + c * 2 + h;
#pragma unroll
      for (int ni = 0; ni < 4; ++ni) {
        const int n = wave * 64 + ni * 16 + l15;
        short8 bfr = *(const short8*)(sWp + ((kg * 4 + quad) * 256 + n) * 8);
        pacc[ni] = MFMA16(afr, bfr, pacc[ni]);
      }
    }
  };

  qkv_gemm(0);
  for (int c = 0; c < 4; ++c) {
    __syncthreads();                  // qkv[c] visible
    attention(c);                     // reads qb/kb/vbT, writes oS
    __syncthreads();                  // oS visible, qkv reads done
    patch_partial(c);                 // reads oS (overlaps next QKV)
    if (c < 3) qkv_gemm(c + 1);       // writes qb/kb/vbT for next chunk
  }

  // epilogue: fb = bp + sum of the 8 bo@Wp_p partials (f32)
  if (quad < 2) {
#pragma unroll
    for (int ni = 0; ni < 4; ++ni) {
      const int n = wave * 64 + ni * 16 + l15;
      float bb = bf2f(CV(bp, n));
#pragma unroll
      for (int p = 0; p < 8; ++p) bb += part[p * 256 + n];
      if (flag) {
        float* po = (float*)out;
#pragma unroll
        for (int r = 0; r < 4; ++r)
          po[(blockIdx.x * 8 + quad * 4 + r) * 256 + n] = pacc[ni][r] + bb;
      } else {
        u16* po = (u16*)out;
#pragma unroll
        for (int r = 0; r < 4; ++r)
          po[(blockIdx.x * 8 + quad * 4 + r) * 256 + n] = f2bf(pacc[ni][r] + bb);
      }
    }
  }
}

extern "C" void kernel_launch(void* const* d_in, const int* in_sizes, int n_in,
                              void* d_out, int out_size, void* d_ws, size_t ws_size,
                              hipStream_t stream) {
  (void)in_sizes; (void)n_in; (void)out_size; (void)ws_size;
  u16* ws = (u16*)d_ws;

  prep_kernel<<<288, 256, 0, stream>>>(
      d_in[0], d_in[1], d_in[2], d_in[3], d_in[4], d_in[5], d_in[6], d_in[7],
      d_in[8], d_in[9], d_in[10], d_in[11], d_in[12], d_in[13], d_in[14], ws);
  fused_kernel<<<3200, 256, 0, stream>>>(
      (const u16*)d_in[0],
      ws + OF_SPEC, ws + OF_SMALL,
      ws + OF_FW, ws + OF_FW + 65536, ws + OF_FW + 2 * 65536, ws + OF_FW + 3 * 65536,
      d_in[14], (const float*)(ws + OF_PART),
      d_out);
}

// Round 4
// 323.334 us; speedup vs baseline: 1.7128x; 1.7128x over previous
//
#include <hip/hip_runtime.h>

typedef unsigned short u16;
typedef __attribute__((ext_vector_type(8))) short short8;
typedef __attribute__((ext_vector_type(4))) short short4_t;
typedef __attribute__((ext_vector_type(4))) float floatx4;

#define MFMA16(A, B, C) __builtin_amdgcn_mfma_f32_16x16x32_bf16((A), (B), (C), 0, 0, 0)

// ws layout (u16 element offsets)
#define OF_SPEC  64                       // canonical bf16 spec [204800]
#define OF_SMALL (OF_SPEC + 204800)       // W1(0) b1(256) fq(512) fk(768) fv(1024)
#define OF_PART  (OF_SMALL + 1536)        // 8x256 f32 partials for fused bp (4096 u16)
#define OF_FW    (OF_PART + 4096)         // fused weights frag-major: Wq' Wk' Wv' (3x65536) + Wp'(524288)
#define OF_ORAW  (OF_FW + 720896)         // o_raw bf16 frag-major [256 kb8][25600 m][8]
#define NPM8     204800                   // 25600 patches * 8

static __device__ __forceinline__ float bf2f(u16 u) {
  union { unsigned int i; float f; } z; z.i = ((unsigned int)u) << 16; return z.f;
}
static __device__ __forceinline__ u16 f2bf(float f) {
  union { float f; unsigned int i; } z; z.f = f;
  unsigned int x = z.i + 0x7fffu + ((z.i >> 16) & 1u);  // RNE
  return (u16)(x >> 16);
}
static __device__ __forceinline__ void ld8f(const u16* p, float* o) {
  union { short8 v; u16 u[8]; } t;
  t.v = *(const short8*)p;
#pragma unroll
  for (int j = 0; j < 8; ++j) o[j] = bf2f(t.u[j]);
}

// bf16 (0) vs f32 (1) input detection on first 256 u16 of spec; per-wave ballot.
static __device__ __forceinline__ int detect_flag(const u16* __restrict__ sp) {
  const int lane = threadIdx.x & 63;
  int bad = 0;
#pragma unroll
  for (int j = 0; j < 4; ++j) {
    u16 v = sp[lane * 4 + j];
    int e = (v >> 7) & 0xFF;
    bad += (e >= 137);
  }
  return (__popcll(__ballot(bad > 0)) >= 4) ? 1 : 0;
}

#define CV(src, idx) (flag ? f2bf(((const float*)(src))[idx]) : ((const u16*)(src))[idx])

// One launch, flag hoisted out of all hot loops:
//   blocks 0..99   : canonicalize spec (8 elems/thread, vectorized)
//   block  100     : canonicalize W1, b1
//   blocks 101..276: 11 fold GEMMs of 256x256x256 (16 sub-blocks of 64x64 each)
//       g=0..2:  Wg' = W2 @ {Wq,Wk,Wv}
//       g=3..10: Wp'_p = Wo @ Wp[p*256:...]
//       written bf16 fragment-major: dst[(k>>3)*2048 + n*8 + (k&7)]
//   blocks 277..287: fused bias vectors fq/fk/fv + 8 f32 partials for fb
__global__ void prep_kernel(
    const void* spec, const void* W1, const void* b1, const void* W2, const void* b2,
    const void* Wq, const void* bq, const void* Wk, const void* bk, const void* Wv,
    const void* bv_, const void* Wo, const void* bo, const void* Wp, const void* bp,
    u16* __restrict__ ws) {
  const int flag = detect_flag((const u16*)spec);
  const int b = blockIdx.x, tid = threadIdx.x;
  if (b < 100) {
    const int i = (b * 256 + tid) * 8;
    union { short8 s8; u16 u[8]; } t;
    if (flag) {
      const float* s = (const float*)spec + i;
      floatx4 v0 = *(const floatx4*)s, v1 = *(const floatx4*)(s + 4);
#pragma unroll
      for (int j = 0; j < 4; ++j) { t.u[j] = f2bf(v0[j]); t.u[4 + j] = f2bf(v1[j]); }
    } else {
      t.s8 = *((const short8*)spec + (b * 256 + tid));
    }
    *(short8*)(ws + OF_SPEC + i) = t.s8;
    return;
  }
  if (b == 100) {
    ws[OF_SMALL + tid] = CV(W1, tid);
    ws[OF_SMALL + 256 + tid] = CV(b1, tid);
    return;
  }
  const int f = b - 101;
  if (f >= 176) {
    const int t = f - 176, n = tid;
    if (t < 3) {
      const void* SB = (t == 0) ? Wq : (t == 1) ? Wk : Wv;
      const void* bs = (t == 0) ? bq : (t == 1) ? bk : bv_;
      float acc;
      if (flag) {
        acc = ((const float*)bs)[n];
        const float* Bf = (const float*)SB; const float* b2f = (const float*)b2;
        for (int k = 0; k < 256; ++k) acc = fmaf(b2f[k], Bf[k * 256 + n], acc);
      } else {
        acc = bf2f(((const u16*)bs)[n]);
        const u16* Bh = (const u16*)SB; const u16* b2h = (const u16*)b2;
        for (int k = 0; k < 256; ++k) acc = fmaf(bf2f(b2h[k]), bf2f(Bh[k * 256 + n]), acc);
      }
      ws[OF_SMALL + 512 + t * 256 + n] = f2bf(acc);
    } else {
      const int p = t - 3;
      float acc = 0.f;
      if (flag) {
        const float* Wf = (const float*)Wp; const float* bf = (const float*)bo;
        for (int m = 0; m < 256; ++m) acc = fmaf(bf[m], Wf[(p * 256 + m) * 256 + n], acc);
      } else {
        const u16* Wh = (const u16*)Wp; const u16* bh = (const u16*)bo;
        for (int m = 0; m < 256; ++m)
          acc = fmaf(bf2f(bh[m]), bf2f(Wh[(p * 256 + m) * 256 + n]), acc);
      }
      ((float*)(ws + OF_PART))[p * 256 + n] = acc;
    }
    return;
  }
  // fold GEMMs
  const int g = f >> 4, sub = f & 15;
  const int r0 = (sub >> 2) * 64, c0 = (sub & 3) * 64;
  const void* SA = (g < 3) ? W2 : Wo;
  const void* SB = (g == 0) ? Wq : (g == 1) ? Wk : (g == 2) ? Wv : Wp;
  const int brow0 = (g < 3) ? 0 : (g - 3) * 256;
  const int w = tid >> 6, lane = tid & 63, l15 = lane & 15, quad = lane >> 4;
  const int arow = r0 + w * 16 + l15;
  floatx4 acc[4];
#pragma unroll
  for (int ni = 0; ni < 4; ++ni) acc[ni] = (floatx4){0.f, 0.f, 0.f, 0.f};
  if (flag) {
    const float* A = (const float*)SA; const float* B = (const float*)SB;
    for (int kc = 0; kc < 8; ++kc) {
      const int k0 = kc * 32 + quad * 8;
      floatx4 a0 = *(const floatx4*)(A + arow * 256 + k0);
      floatx4 a1 = *(const floatx4*)(A + arow * 256 + k0 + 4);
      union { short8 s8; u16 u[8]; } av;
#pragma unroll
      for (int j = 0; j < 4; ++j) { av.u[j] = f2bf(a0[j]); av.u[4 + j] = f2bf(a1[j]); }
#pragma unroll
      for (int ni = 0; ni < 4; ++ni) {
        const int colx = c0 + ni * 16 + l15;
        union { short8 s8; u16 u[8]; } bu;
#pragma unroll
        for (int j = 0; j < 8; ++j) bu.u[j] = f2bf(B[(brow0 + k0 + j) * 256 + colx]);
        acc[ni] = MFMA16(av.s8, bu.s8, acc[ni]);
      }
    }
  } else {
    const u16* A = (const u16*)SA; const u16* B = (const u16*)SB;
    for (int kc = 0; kc < 8; ++kc) {
      const int k0 = kc * 32 + quad * 8;
      short8 av = *(const short8*)(A + arow * 256 + k0);
#pragma unroll
      for (int ni = 0; ni < 4; ++ni) {
        const int colx = c0 + ni * 16 + l15;
        union { short8 s8; u16 u[8]; } bu;
#pragma unroll
        for (int j = 0; j < 8; ++j) bu.u[j] = B[(brow0 + k0 + j) * 256 + colx];
        acc[ni] = MFMA16(av, bu.s8, acc[ni]);
      }
    }
  }
  u16* dst = ws + OF_FW + ((g < 3) ? g * 65536 : 3 * 65536);
#pragma unroll
  for (int ni = 0; ni < 4; ++ni) {
    const int n = c0 + ni * 16 + l15;
#pragma unroll
    for (int r = 0; r < 4; ++r) {
      const int k = brow0 + r0 + w * 16 + quad * 4 + r;
      dst[(k >> 3) * 2048 + n * 8 + (k & 7)] = f2bf(acc[ni][r]);
    }
  }
}

// One block = 64 tokens = 8 windows: embed + QKV + MFMA attention only.
// Raw attention output o (pre-Wo') written bf16 to o_raw in GEMM-fragment-major
// layout: u16 idx = (k>>3)*NPM8 + m*8 + (k&7), k = p*256 + D, m = global patch.
__global__ __launch_bounds__(256, 2) void fused_lite_kernel(
    const u16* __restrict__ csp, const u16* __restrict__ csm,
    const u16* __restrict__ sWq, const u16* __restrict__ sWk,
    const u16* __restrict__ sWv,
    u16* __restrict__ oraw)
{
  __shared__ u16 lds[28672];          // 57344 B -> 2 blocks/CU
  u16* aA  = lds;                     // 16384: frag-major a[m<64][k<256]
  u16* qb  = lds + 16384;             // 64 x 64, XOR-swizzled cols (+ wave-local P scratch)
  u16* kb  = qb + 4096;
  u16* vbT = kb + 4096;               // transposed V, swizzled tok-blocks

  const u16* cW1 = csm;
  const u16* cb1 = csm + 256;
  const u16* cfq = csm + 512;
  const u16* cfk = csm + 768;
  const u16* cfv = csm + 1024;

  const int tid = threadIdx.x;
  const int wave = tid >> 6, lane = tid & 63;
  const int l15 = lane & 15, quad = lane >> 4;
  const int tile0 = blockIdx.x * 64;
  const floatx4 zero4 = (floatx4){0.f, 0.f, 0.f, 0.f};

  // ---------------- a-fill: relu(s*W1+b1) -> aA fragment-major ----------------
  {
    const int m = tid & 63;
    const int k8base = (tid >> 6) * 8;
    const float s = bf2f(csp[tile0 + m]);
#pragma unroll
    for (int c = 0; c < 8; ++c) {
      const int k8 = k8base + c;
      float w1f[8], b1f[8];
      ld8f(cW1 + k8 * 8, w1f);
      ld8f(cb1 + k8 * 8, b1f);
      union { short8 s8; u16 u[8]; } t;
#pragma unroll
      for (int j = 0; j < 8; ++j) {
        float x = fmaf(s, w1f[j], b1f[j]);
        t.u[j] = f2bf(x > 0.f ? x : 0.f);
      }
      *(short8*)(aA + k8 * 512 + m * 8) = t.s8;
    }
  }
  __syncthreads();

  unsigned opk[32];                   // packed bf16 attention outputs (2 per PV MFMA)

  // ---------------- 4 chunks of 2 heads (64 cols) each ------------------
#pragma unroll
  for (int c = 0; c < 4; ++c) {
    const int col = c * 64 + wave * 16 + l15;

    // q,k,v GEMMs (fused weights: K=256 over a)
    {
      floatx4 facc[3][4];
#pragma unroll
      for (int x = 0; x < 3; ++x)
#pragma unroll
        for (int mi = 0; mi < 4; ++mi) facc[x][mi] = zero4;
      for (int kc = 0; kc < 8; ++kc) {
        short8 afr[4];
#pragma unroll
        for (int mi = 0; mi < 4; ++mi)
          afr[mi] = *(const short8*)(aA + (kc * 4 + quad) * 512 + (mi * 16 + l15) * 8);
        const int wo = ((kc * 4 + quad) * 256 + col) * 8;
        short8 bq8 = *(const short8*)(sWq + wo);
        short8 bk8 = *(const short8*)(sWk + wo);
        short8 bv8 = *(const short8*)(sWv + wo);
#pragma unroll
        for (int mi = 0; mi < 4; ++mi) {
          facc[0][mi] = MFMA16(afr[mi], bq8, facc[0][mi]);
          facc[1][mi] = MFMA16(afr[mi], bk8, facc[1][mi]);
          facc[2][mi] = MFMA16(afr[mi], bv8, facc[2][mi]);
        }
      }
      const int lc = wave * 16 + l15;
      const float bqv = bf2f(cfq[col]), bkv = bf2f(cfk[col]), bvv = bf2f(cfv[col]);
#pragma unroll
      for (int mi = 0; mi < 4; ++mi) {
#pragma unroll
        for (int r = 0; r < 4; ++r) {
          const int tr = mi * 16 + quad * 4 + r;
          const int rr = tr * 64 + ((((lc >> 3) ^ (tr & 7)) << 3) | (lc & 7));
          qb[rr] = f2bf(facc[0][mi][r] + bqv);
          kb[rr] = f2bf(facc[1][mi][r] + bkv);
        }
        union { short4_t s4; u16 u[4]; } tv;
#pragma unroll
        for (int r = 0; r < 4; ++r) tv.u[r] = f2bf(facc[2][mi][r] + bvv);
        *(short4_t*)(vbT + lc * 64 + (((mi * 2 + (quad >> 1)) ^ (lc & 7)) << 3) +
                     (quad & 1) * 4) = tv.s4;
      }
    }
    __syncthreads();

    // ---- MFMA attention: wave w owns windows {2w, 2w+1}, both heads ----
    {
      const int w2 = wave * 2;
      const int rq = (wave * 16 + l15) * 64;
      u16* pscr = qb + wave * 1024;   // aliases this wave's own Q rows (reads done first)
      const int validk = ((l15 >> 3) == (quad >> 1));

      floatx4 sc2[2];
#pragma unroll
      for (int hl = 0; hl < 2; ++hl) {
        const int c8s = (((hl * 4 + quad) ^ (l15 & 7)) << 3);
        short8 qf = *(const short8*)(qb + rq + c8s);
        short8 kf = *(const short8*)(kb + rq + c8s);
        sc2[hl] = MFMA16(qf, kf, zero4);
      }
      u16 pb[2][4];
#pragma unroll
      for (int hl = 0; hl < 2; ++hl) {
#pragma unroll
        for (int r = 0; r < 4; ++r) {
          float s = sc2[hl][r] * 0.17677669529663687f;   // 1/sqrt(32)
          float mx = fmaxf(s, __shfl_xor(s, 1));
          mx = fmaxf(mx, __shfl_xor(mx, 2));
          mx = fmaxf(mx, __shfl_xor(mx, 4));
          float p = __expf(s - mx);
          float sum = p + __shfl_xor(p, 1);
          sum += __shfl_xor(sum, 2);
          sum += __shfl_xor(sum, 4);
          pb[hl][r] = f2bf(validk ? p / sum : 0.f);
        }
      }
#pragma unroll
      for (int hl = 0; hl < 2; ++hl)
#pragma unroll
        for (int r = 0; r < 4; ++r)
          pscr[hl * 256 + (quad * 4 + r) * 16 + l15] = pb[hl][r];

#pragma unroll
      for (int hl = 0; hl < 2; ++hl) {
#pragma unroll
        for (int dh = 0; dh < 2; ++dh) {
          const int vcol = hl * 32 + dh * 16 + l15;
          short8 pa = (short8){0, 0, 0, 0, 0, 0, 0, 0};
          short8 vf = (short8){0, 0, 0, 0, 0, 0, 0, 0};
          if (quad < 2) {
            pa = *(const short8*)(pscr + hl * 256 + l15 * 16 + quad * 8);
            vf = *(const short8*)(vbT + vcol * 64 + (((w2 + quad) ^ (vcol & 7)) << 3));
          }
          floatx4 o = MFMA16(pa, vf, zero4);
          const int oi = ((c * 2 + hl) * 2 + dh) * 2;
          opk[oi]     = (unsigned)f2bf(o[0]) | ((unsigned)f2bf(o[1]) << 16);
          opk[oi + 1] = (unsigned)f2bf(o[2]) | ((unsigned)f2bf(o[3]) << 16);
        }
      }
    }
    if (c < 3) __syncthreads();
  }

  // opk -> o_raw (global, fragment-major). Per PV MFMA: token row = quad*4+r in
  // the window pair -> win = 2*wave + (quad>>1), p = (quad&1)*4 + r;
  // D = c*64 + hl*32 + dh*16 + l15.
  {
    const int mbase = (blockIdx.x * 8 + wave * 2 + (quad >> 1)) * 8 + (l15 & 7);
    const int pb4 = (quad & 1) * 4;
#pragma unroll
    for (int c = 0; c < 4; ++c)
#pragma unroll
      for (int hl = 0; hl < 2; ++hl)
#pragma unroll
        for (int dh = 0; dh < 2; ++dh) {
          const int oi = ((c * 2 + hl) * 2 + dh) * 2;
          const int e8 = c * 8 + hl * 4 + dh * 2 + (l15 >> 3);
          const unsigned lo = opk[oi], hi = opk[oi + 1];
          oraw[((pb4 + 0) * 32 + e8) * NPM8 + mbase] = (u16)lo;
          oraw[((pb4 + 1) * 32 + e8) * NPM8 + mbase] = (u16)(lo >> 16);
          oraw[((pb4 + 2) * 32 + e8) * NPM8 + mbase] = (u16)hi;
          oraw[((pb4 + 3) * 32 + e8) * NPM8 + mbase] = (u16)(hi >> 16);
        }
  }
}

// Patch projection as a real GEMM: [25600 x 2048] @ Wp' [2048 x 256] + fb.
// M-tile 32, N-tile 128, 4 waves each 32x32; A and B read directly from global
// (both fragment-major, coalesced b128); no LDS.
__global__ __launch_bounds__(256) void patch_gemm_kernel(
    const u16* __restrict__ spec_raw,
    const u16* __restrict__ oraw, const u16* __restrict__ sWp,
    const void* __restrict__ bp, const float* __restrict__ part,
    void* __restrict__ out)
{
  const int flag = detect_flag(spec_raw);
  const int tid = threadIdx.x;
  const int wave = tid >> 6, lane = tid & 63;
  const int l15 = lane & 15, quad = lane >> 4;
  const int m0 = (blockIdx.x >> 1) * 32;
  const int n0 = (blockIdx.x & 1) * 128 + wave * 32;
  const floatx4 zero4 = (floatx4){0.f, 0.f, 0.f, 0.f};

  floatx4 acc[2][2];
#pragma unroll
  for (int mi = 0; mi < 2; ++mi)
#pragma unroll
    for (int ni = 0; ni < 2; ++ni) acc[mi][ni] = zero4;

  const u16* ap = oraw + quad * NPM8 + (m0 + l15) * 8;
  const u16* bpw = sWp + quad * 2048 + (n0 + l15) * 8;
#pragma unroll 4
  for (int kk = 0; kk < 64; ++kk) {
    short8 a0 = *(const short8*)(ap);
    short8 a1 = *(const short8*)(ap + 128);          // +16 rows
    short8 b0 = *(const short8*)(bpw);
    short8 b1 = *(const short8*)(bpw + 128);         // +16 cols
    ap += 4 * NPM8;
    bpw += 4 * 2048;
    acc[0][0] = MFMA16(a0, b0, acc[0][0]);
    acc[0][1] = MFMA16(a0, b1, acc[0][1]);
    acc[1][0] = MFMA16(a1, b0, acc[1][0]);
    acc[1][1] = MFMA16(a1, b1, acc[1][1]);
  }

  // epilogue: fb = bp + sum of the 8 bo@Wp_p partials (f32)
#pragma unroll
  for (int ni = 0; ni < 2; ++ni) {
    const int n = n0 + ni * 16 + l15;
    float bb = bf2f(CV(bp, n));
#pragma unroll
    for (int p = 0; p < 8; ++p) bb += part[p * 256 + n];
#pragma unroll
    for (int mi = 0; mi < 2; ++mi) {
      const int mr = m0 + mi * 16 + quad * 4;
      if (flag) {
        float* po = (float*)out;
#pragma unroll
        for (int r = 0; r < 4; ++r)
          po[(mr + r) * 256 + n] = acc[mi][ni][r] + bb;
      } else {
        u16* po = (u16*)out;
#pragma unroll
        for (int r = 0; r < 4; ++r)
          po[(mr + r) * 256 + n] = f2bf(acc[mi][ni][r] + bb);
      }
    }
  }
}

// Fallback (ws too small for o_raw): round-2 fully-fused kernel, patch included.
__global__ __launch_bounds__(256, 2) void fused_full_kernel(
    const u16* __restrict__ spec_raw,
    const u16* __restrict__ csp, const u16* __restrict__ csm,
    const u16* __restrict__ sWq, const u16* __restrict__ sWk,
    const u16* __restrict__ sWv, const u16* __restrict__ sWp,
    const void* __restrict__ bp, const float* __restrict__ part,
    void* __restrict__ out)
{
  __shared__ u16 lds[28672];
  u16* aA  = lds;
  u16* qb  = lds + 16384;
  u16* kb  = qb + 4096;
  u16* vbT = kb + 4096;

  const u16* cW1 = csm;
  const u16* cb1 = csm + 256;
  const u16* cfq = csm + 512;
  const u16* cfk = csm + 768;
  const u16* cfv = csm + 1024;

  const int flag = detect_flag(spec_raw);
  const int tid = threadIdx.x;
  const int wave = tid >> 6, lane = tid & 63;
  const int l15 = lane & 15, quad = lane >> 4;
  const int tile0 = blockIdx.x * 64;
  const floatx4 zero4 = (floatx4){0.f, 0.f, 0.f, 0.f};

  {
    const int m = tid & 63;
    const int k8base = (tid >> 6) * 8;
    const float s = bf2f(csp[tile0 + m]);
#pragma unroll
    for (int c = 0; c < 8; ++c) {
      const int k8 = k8base + c;
      float w1f[8], b1f[8];
      ld8f(cW1 + k8 * 8, w1f);
      ld8f(cb1 + k8 * 8, b1f);
      union { short8 s8; u16 u[8]; } t;
#pragma unroll
      for (int j = 0; j < 8; ++j) {
        float x = fmaf(s, w1f[j], b1f[j]);
        t.u[j] = f2bf(x > 0.f ? x : 0.f);
      }
      *(short8*)(aA + k8 * 512 + m * 8) = t.s8;
    }
  }
  __syncthreads();

  unsigned opk[32];

#pragma unroll
  for (int c = 0; c < 4; ++c) {
    const int col = c * 64 + wave * 16 + l15;
    {
      floatx4 facc[3][4];
#pragma unroll
      for (int x = 0; x < 3; ++x)
#pragma unroll
        for (int mi = 0; mi < 4; ++mi) facc[x][mi] = zero4;
      for (int kc = 0; kc < 8; ++kc) {
        short8 afr[4];
#pragma unroll
        for (int mi = 0; mi < 4; ++mi)
          afr[mi] = *(const short8*)(aA + (kc * 4 + quad) * 512 + (mi * 16 + l15) * 8);
        const int wo = ((kc * 4 + quad) * 256 + col) * 8;
        short8 bq8 = *(const short8*)(sWq + wo);
        short8 bk8 = *(const short8*)(sWk + wo);
        short8 bv8 = *(const short8*)(sWv + wo);
#pragma unroll
        for (int mi = 0; mi < 4; ++mi) {
          facc[0][mi] = MFMA16(afr[mi], bq8, facc[0][mi]);
          facc[1][mi] = MFMA16(afr[mi], bk8, facc[1][mi]);
          facc[2][mi] = MFMA16(afr[mi], bv8, facc[2][mi]);
        }
      }
      const int lc = wave * 16 + l15;
      const float bqv = bf2f(cfq[col]), bkv = bf2f(cfk[col]), bvv = bf2f(cfv[col]);
#pragma unroll
      for (int mi = 0; mi < 4; ++mi) {
#pragma unroll
        for (int r = 0; r < 4; ++r) {
          const int tr = mi * 16 + quad * 4 + r;
          const int rr = tr * 64 + ((((lc >> 3) ^ (tr & 7)) << 3) | (lc & 7));
          qb[rr] = f2bf(facc[0][mi][r] + bqv);
          kb[rr] = f2bf(facc[1][mi][r] + bkv);
        }
        union { short4_t s4; u16 u[4]; } tv;
#pragma unroll
        for (int r = 0; r < 4; ++r) tv.u[r] = f2bf(facc[2][mi][r] + bvv);
        *(short4_t*)(vbT + lc * 64 + (((mi * 2 + (quad >> 1)) ^ (lc & 7)) << 3) +
                     (quad & 1) * 4) = tv.s4;
      }
    }
    __syncthreads();
    {
      const int w2 = wave * 2;
      const int rq = (wave * 16 + l15) * 64;
      u16* pscr = qb + wave * 1024;
      const int validk = ((l15 >> 3) == (quad >> 1));

      floatx4 sc2[2];
#pragma unroll
      for (int hl = 0; hl < 2; ++hl) {
        const int c8s = (((hl * 4 + quad) ^ (l15 & 7)) << 3);
        short8 qf = *(const short8*)(qb + rq + c8s);
        short8 kf = *(const short8*)(kb + rq + c8s);
        sc2[hl] = MFMA16(qf, kf, zero4);
      }
      u16 pb[2][4];
#pragma unroll
      for (int hl = 0; hl < 2; ++hl) {
#pragma unroll
        for (int r = 0; r < 4; ++r) {
          float s = sc2[hl][r] * 0.17677669529663687f;
          float mx = fmaxf(s, __shfl_xor(s, 1));
          mx = fmaxf(mx, __shfl_xor(mx, 2));
          mx = fmaxf(mx, __shfl_xor(mx, 4));
          float p = __expf(s - mx);
          float sum = p + __shfl_xor(p, 1);
          sum += __shfl_xor(sum, 2);
          sum += __shfl_xor(sum, 4);
          pb[hl][r] = f2bf(validk ? p / sum : 0.f);
        }
      }
#pragma unroll
      for (int hl = 0; hl < 2; ++hl)
#pragma unroll
        for (int r = 0; r < 4; ++r)
          pscr[hl * 256 + (quad * 4 + r) * 16 + l15] = pb[hl][r];

#pragma unroll
      for (int hl = 0; hl < 2; ++hl) {
#pragma unroll
        for (int dh = 0; dh < 2; ++dh) {
          const int vcol = hl * 32 + dh * 16 + l15;
          short8 pa = (short8){0, 0, 0, 0, 0, 0, 0, 0};
          short8 vf = (short8){0, 0, 0, 0, 0, 0, 0, 0};
          if (quad < 2) {
            pa = *(const short8*)(pscr + hl * 256 + l15 * 16 + quad * 8);
            vf = *(const short8*)(vbT + vcol * 64 + (((w2 + quad) ^ (vcol & 7)) << 3));
          }
          floatx4 o = MFMA16(pa, vf, zero4);
          const int oi = ((c * 2 + hl) * 2 + dh) * 2;
          opk[oi]     = (unsigned)f2bf(o[0]) | ((unsigned)f2bf(o[1]) << 16);
          opk[oi + 1] = (unsigned)f2bf(o[2]) | ((unsigned)f2bf(o[3]) << 16);
        }
      }
    }
    if (c < 3) __syncthreads();
  }

  {
    const int abase = (2 * wave + (quad >> 1)) * 8 + (l15 & 7) + ((l15 >> 3) << 6);
    const int pb4 = (quad & 1) * 4;
#pragma unroll
    for (int i16 = 0; i16 < 16; ++i16) {
      const unsigned lo = opk[i16 * 2], hi = opk[i16 * 2 + 1];
      u16* q0 = aA + abase + i16 * 128 + pb4 * 2048;
      q0[0]        = (u16)lo;
      q0[2048]     = (u16)(lo >> 16);
      q0[2 * 2048] = (u16)hi;
      q0[3 * 2048] = (u16)(hi >> 16);
    }
  }
  __syncthreads();

  {
    const int w8 = (l15 & 7) * 8;
    floatx4 pacc[4];
#pragma unroll
    for (int ni = 0; ni < 4; ++ni) pacc[ni] = zero4;
#pragma unroll 4
    for (int kc = 0; kc < 64; ++kc) {
      short8 afr = *(const short8*)(aA + (kc * 4 + quad) * 64 + w8);
#pragma unroll
      for (int ni = 0; ni < 4; ++ni) {
        const int n = wave * 64 + ni * 16 + l15;
        short8 bfr = *(const short8*)(sWp + ((kc * 4 + quad) * 256 + n) * 8);
        pacc[ni] = MFMA16(afr, bfr, pacc[ni]);
      }
    }
    if (quad < 2) {
#pragma unroll
      for (int ni = 0; ni < 4; ++ni) {
        const int n = wave * 64 + ni * 16 + l15;
        float bb = bf2f(CV(bp, n));
#pragma unroll
        for (int p = 0; p < 8; ++p) bb += part[p * 256 + n];
        if (flag) {
          float* po = (float*)out;
#pragma unroll
          for (int r = 0; r < 4; ++r)
            po[(blockIdx.x * 8 + quad * 4 + r) * 256 + n] = pacc[ni][r] + bb;
        } else {
          u16* po = (u16*)out;
#pragma unroll
          for (int r = 0; r < 4; ++r)
            po[(blockIdx.x * 8 + quad * 4 + r) * 256 + n] = f2bf(pacc[ni][r] + bb);
        }
      }
    }
  }
}

extern "C" void kernel_launch(void* const* d_in, const int* in_sizes, int n_in,
                              void* d_out, int out_size, void* d_ws, size_t ws_size,
                              hipStream_t stream) {
  (void)in_sizes; (void)n_in; (void)out_size;
  u16* ws = (u16*)d_ws;

  prep_kernel<<<288, 256, 0, stream>>>(
      d_in[0], d_in[1], d_in[2], d_in[3], d_in[4], d_in[5], d_in[6], d_in[7],
      d_in[8], d_in[9], d_in[10], d_in[11], d_in[12], d_in[13], d_in[14], ws);

  const size_t need = ((size_t)OF_ORAW + (size_t)256 * NPM8) * sizeof(u16);
  if (ws_size >= need) {
    fused_lite_kernel<<<3200, 256, 0, stream>>>(
        ws + OF_SPEC, ws + OF_SMALL,
        ws + OF_FW, ws + OF_FW + 65536, ws + OF_FW + 2 * 65536,
        ws + OF_ORAW);
    patch_gemm_kernel<<<1600, 256, 0, stream>>>(
        (const u16*)d_in[0],
        ws + OF_ORAW, ws + OF_FW + 3 * 65536,
        d_in[14], (const float*)(ws + OF_PART),
        d_out);
  } else {
    fused_full_kernel<<<3200, 256, 0, stream>>>(
        (const u16*)d_in[0],
        ws + OF_SPEC, ws + OF_SMALL,
        ws + OF_FW, ws + OF_FW + 65536, ws + OF_FW + 2 * 65536, ws + OF_FW + 3 * 65536,
        d_in[14], (const float*)(ws + OF_PART),
        d_out);
  }
}